// Round 6
// baseline (9471.535 us; speedup 1.0000x reference)
//
#include <hip/hip_runtime.h>
#include <hip/hip_bf16.h>
#include <cstdint>
#include <cstddef>

// LSTM w/ projection + peepholes, MI355X gfx950.  T=512 N=32 D=H=P=1024 L=4.
// m = o*tanh(c) passed between layers/steps; projection folded into weights:
//   W1^l = whm^{l-1} @ wih^l (l>=1; layer0 uses wih0), W2^l = whm^l @ whh^l
// R5/R6: persistent kernel launched via hipLaunchCooperativeKernel
// (co-residency guaranteed by the runtime); agent-scope atomic grid barrier
// per slot; each block's 256KB Wcat slice held in 128 VGPRs; cell state /
// bias / peephole weights register-resident.
//
// Workspace layout (bytes):
//   0           Wcat    67,108,864  bf16 [l][4096][2048]
//   67,108,864  m3      33,554,432  bf16 (ALIAS precompute: wihT l=1..3)
//   100,663,296 xbf     33,554,432  bf16 (ALIAS precompute: whhT l=0..3)
//   134,217,728 whm_bf   8,388,608
//   142,606,336 whmT_bf  8,388,608
//   150,994,944 ring       393,216
//   151,388,160 r0       2,097,152
//   153,485,312 bias        65,536
//   153,550,848 sync         1,024

#define TT 512
#define NBATCH 32
#define HID 1024
#define G4 4096
#define KCAT 2048

typedef __attribute__((ext_vector_type(4))) float f32x4;
typedef __attribute__((ext_vector_type(8))) short bf16x8;

static __device__ __forceinline__ uint16_t f2bf(float f) {
  uint32_t u = __builtin_bit_cast(uint32_t, f);
  uint32_t lsb = (u >> 16) & 1u;
  u += 0x7fffu + lsb;  // RNE
  return (uint16_t)(u >> 16);
}

static __device__ __forceinline__ f32x4 mfma16x16(bf16x8 a, bf16x8 b, f32x4 c) {
  return __builtin_amdgcn_mfma_f32_16x16x32_bf16(a, b, c, 0, 0, 0);
}

static __device__ __forceinline__ float sigm(float v) { return 1.f / (1.f + __expf(-v)); }
static __device__ __forceinline__ float tanh_(float v) {
  float a = fabsf(v);
  float e = __expf(-2.f * a);
  float t = (1.f - e) / (1.f + e);
  return v < 0.f ? -t : t;
}

// ---------------- small helpers ----------------
__global__ void __launch_bounds__(256) add_bias(const float* __restrict__ a,
                                                const float* __restrict__ b,
                                                float* __restrict__ o, int n) {
  int i = blockIdx.x * 256 + threadIdx.x;
  if (i < n) o[i] = a[i] + b[i];
}

__global__ void __launch_bounds__(256) cast_bf16(const float* __restrict__ src,
                                                 uint16_t* __restrict__ dst, int n8) {
  int i = blockIdx.x * 256 + threadIdx.x;
  if (i >= n8) return;
  const float* s = src + (size_t)i * 8;
  f32x4 v0 = *(const f32x4*)s;
  f32x4 v1 = *(const f32x4*)(s + 4);
  bf16x8 o;
  o[0] = (short)f2bf(v0[0]); o[1] = (short)f2bf(v0[1]);
  o[2] = (short)f2bf(v0[2]); o[3] = (short)f2bf(v0[3]);
  o[4] = (short)f2bf(v1[0]); o[5] = (short)f2bf(v1[1]);
  o[6] = (short)f2bf(v1[2]); o[7] = (short)f2bf(v1[3]);
  *(bf16x8*)(dst + (size_t)i * 8) = o;
}

// src f32 (K x N) row-major -> dst bf16 [n][k] (ld ldd), 64x64 tiles
__global__ void __launch_bounds__(256) transpose_cast(const float* __restrict__ src, int lds,
                                                      uint16_t* __restrict__ dst, int ldd) {
  const int k0 = blockIdx.x * 64;
  const int n0 = blockIdx.y * 64;
  __shared__ float tile[64][65];
  const int tid = threadIdx.x;
#pragma unroll
  for (int p = 0; p < 4; ++p) {
    int kk = (tid >> 4) + 16 * p, nq = tid & 15;
    f32x4 v = *(const f32x4*)(src + (size_t)(k0 + kk) * lds + n0 + 4 * nq);
#pragma unroll
    for (int j = 0; j < 4; ++j) tile[kk][4 * nq + j] = v[j];
  }
  __syncthreads();
#pragma unroll
  for (int p = 0; p < 2; ++p) {
    int nn = (tid >> 3) + 32 * p, kq = tid & 7;
    bf16x8 o;
#pragma unroll
    for (int i = 0; i < 8; ++i) o[i] = (short)f2bf(tile[8 * kq + i][nn]);
    *(bf16x8*)(dst + (size_t)(n0 + nn) * ldd + k0 + 8 * kq) = o;
  }
}

// ---------------- tiled GEMM: C[M][N] = A[M][K]bf16 @ Bt[N][K]bf16^T ----------------
template <bool OBF16>
__global__ void __launch_bounds__(256) gemm_tn(const uint16_t* __restrict__ A, int lda, int M,
                                               const uint16_t* __restrict__ Bt, int ldb,
                                               void* __restrict__ Cp, int ldc, int K) {
  const int m0 = blockIdx.x * 128, n0 = blockIdx.y * 128;
  __shared__ __align__(16) uint16_t As[128 * 40];
  __shared__ __align__(16) uint16_t Bs[128 * 40];
  const int tid = threadIdx.x;
  const int w = tid >> 6, lane = tid & 63, r16 = lane & 15, g = lane >> 4;
  f32x4 acc[4][4];
#pragma unroll
  for (int a = 0; a < 4; ++a)
#pragma unroll
    for (int b = 0; b < 4; ++b) acc[a][b] = (f32x4){0.f, 0.f, 0.f, 0.f};

  for (int k0 = 0; k0 < K; k0 += 32) {
#pragma unroll
    for (int q = 0; q < 2; ++q) {
      int c = q * 256 + tid, row = c >> 2, col = (c & 3) * 8;
      bf16x8 va = (bf16x8){0, 0, 0, 0, 0, 0, 0, 0};
      if (m0 + row < M) va = *(const bf16x8*)(A + (size_t)(m0 + row) * lda + k0 + col);
      *(bf16x8*)(As + row * 40 + col) = va;
      bf16x8 vb = *(const bf16x8*)(Bt + (size_t)(n0 + row) * ldb + k0 + col);
      *(bf16x8*)(Bs + row * 40 + col) = vb;
    }
    __syncthreads();
    bf16x8 bfr[4];
#pragma unroll
    for (int nf = 0; nf < 4; ++nf)
      bfr[nf] = *(const bf16x8*)(Bs + ((w >> 1) * 64 + nf * 16 + r16) * 40 + 8 * g);
#pragma unroll
    for (int mf = 0; mf < 4; ++mf) {
      bf16x8 a = *(const bf16x8*)(As + ((w & 1) * 64 + mf * 16 + r16) * 40 + 8 * g);
#pragma unroll
      for (int nf = 0; nf < 4; ++nf) acc[mf][nf] = mfma16x16(a, bfr[nf], acc[mf][nf]);
    }
    __syncthreads();
  }
#pragma unroll
  for (int mf = 0; mf < 4; ++mf)
#pragma unroll
    for (int nf = 0; nf < 4; ++nf)
#pragma unroll
      for (int reg = 0; reg < 4; ++reg) {
        int row = m0 + (w & 1) * 64 + mf * 16 + (lane >> 4) * 4 + reg;
        int col = n0 + (w >> 1) * 64 + nf * 16 + (lane & 15);
        if (row < M) {
          if (OBF16)
            ((uint16_t*)Cp)[(size_t)row * ldc + col] = f2bf(acc[mf][nf][reg]);
          else
            ((float*)Cp)[(size_t)row * ldc + col] = acc[mf][nf][reg];
        }
      }
}

// ---------------- f32 GEMM for r0 = h0 @ whh (M=32) ----------------
__global__ void __launch_bounds__(256) gemm32_f32(const float* __restrict__ A, int lda,
                                                  const float* __restrict__ B, int ldb,
                                                  float* __restrict__ C, int ldc, int K) {
  const int n0 = blockIdx.x * 64;
  __shared__ __align__(16) uint16_t As[32 * 40];
  __shared__ __align__(16) uint16_t Bs[64 * 40];
  const int tid = threadIdx.x;
  const int w = tid >> 6, lane = tid & 63, r16 = lane & 15, g = lane >> 4;
  f32x4 acc[2];
  acc[0] = (f32x4){0.f, 0.f, 0.f, 0.f};
  acc[1] = acc[0];
  for (int k0 = 0; k0 < K; k0 += 32) {
    {
      int m = tid >> 3, kq = tid & 7;
      f32x4 v = *(const f32x4*)(A + (size_t)m * lda + k0 + 4 * kq);
      uint64_t pk = (uint64_t)f2bf(v[0]) | ((uint64_t)f2bf(v[1]) << 16) |
                    ((uint64_t)f2bf(v[2]) << 32) | ((uint64_t)f2bf(v[3]) << 48);
      *(uint64_t*)(As + m * 40 + 4 * kq) = pk;
    }
#pragma unroll
    for (int p = 0; p < 2; ++p) {
      int k = (tid >> 4) + 16 * p, nq = tid & 15;
      f32x4 v = *(const f32x4*)(B + (size_t)(k0 + k) * ldb + n0 + 4 * nq);
#pragma unroll
      for (int j = 0; j < 4; ++j) Bs[(4 * nq + j) * 40 + k] = f2bf(v[j]);
    }
    __syncthreads();
    bf16x8 a0 = *(const bf16x8*)(As + r16 * 40 + 8 * g);
    bf16x8 a1 = *(const bf16x8*)(As + (r16 + 16) * 40 + 8 * g);
    bf16x8 b = *(const bf16x8*)(Bs + (16 * w + r16) * 40 + 8 * g);
    acc[0] = mfma16x16(a0, b, acc[0]);
    acc[1] = mfma16x16(a1, b, acc[1]);
    __syncthreads();
  }
#pragma unroll
  for (int rt = 0; rt < 2; ++rt)
#pragma unroll
    for (int reg = 0; reg < 4; ++reg)
      C[(size_t)(16 * rt + 4 * g + reg) * ldc + n0 + 16 * w + r16] = acc[rt][reg];
}

// ---------------- grid barrier (two-level, agent scope) ----------------
// Co-residency is guaranteed by hipLaunchCooperativeKernel; this barrier
// only has to be correct given co-residency (memory-model chain:
// grp-reset -> root ACQ_REL -> gen RELEASE -> spinner ACQUIRE).
static __device__ __forceinline__ void grid_barrier(uint32_t* sync) {
  __syncthreads();
  if (threadIdx.x == 0) {
    uint32_t* grp = sync + 16 * (blockIdx.x >> 5);  // 8 groups of 32, 64B apart
    uint32_t* root = sync + 128;
    uint32_t* gen = sync + 144;
    uint32_t g = __hip_atomic_load(gen, __ATOMIC_RELAXED, __HIP_MEMORY_SCOPE_AGENT);
    uint32_t v = __hip_atomic_fetch_add(grp, 1u, __ATOMIC_ACQ_REL, __HIP_MEMORY_SCOPE_AGENT);
    bool bumped = false;
    if (v == 31u) {
      __hip_atomic_store(grp, 0u, __ATOMIC_RELAXED, __HIP_MEMORY_SCOPE_AGENT);
      uint32_t r = __hip_atomic_fetch_add(root, 1u, __ATOMIC_ACQ_REL, __HIP_MEMORY_SCOPE_AGENT);
      if (r == 7u) {
        __hip_atomic_store(root, 0u, __ATOMIC_RELAXED, __HIP_MEMORY_SCOPE_AGENT);
        __hip_atomic_fetch_add(gen, 1u, __ATOMIC_RELEASE, __HIP_MEMORY_SCOPE_AGENT);
        bumped = true;
      }
    }
    if (!bumped) {
      uint32_t cur;
      do {
        __builtin_amdgcn_s_sleep(2);
        cur = __hip_atomic_load(gen, __ATOMIC_RELAXED, __HIP_MEMORY_SCOPE_AGENT);
      } while (cur == g);
      (void)__hip_atomic_load(gen, __ATOMIC_ACQUIRE, __HIP_MEMORY_SCOPE_AGENT);
    }
  }
  __syncthreads();
}

// ---------------- persistent recurrence kernel ----------------
// 256 blocks x 512 thr (8 waves). block = (layer l=blk>>6, h-slice slc=blk&63).
// Wcat slice (256KB) pre-loaded into 128 VGPRs/thread; c, bias, peepholes in
// registers. Per slot: A read from global (L2-hot), MFMA vs register-B, LDS
// cross-wave reduce, pointwise, m write; then grid barrier.
__global__ void __launch_bounds__(512, 2) lstm_persist(
    const uint16_t* __restrict__ xbf, const float* __restrict__ wic,
    const float* __restrict__ wfc, const float* __restrict__ woc,
    const float* __restrict__ r0, const float* __restrict__ bias,
    const float* __restrict__ c0, float* __restrict__ cs,
    const uint16_t* __restrict__ Wcat, uint16_t* __restrict__ ring,
    uint16_t* __restrict__ m3, uint32_t* __restrict__ sync) {
  const int blk = blockIdx.x;
  const int l = blk >> 6, slc = blk & 63;
  const int j0 = slc * 16;
  const int tid = threadIdx.x;
  const int w = tid >> 6, lane = tid & 63, r16 = lane & 15, g = lane >> 4;
  __shared__ __align__(16) float red[16384];

  // ---- B preload into registers: [phase][i][gate], 128 VGPRs ----
  const uint16_t* Wl = Wcat + (size_t)l * G4 * KCAT;
  bf16x8 breg[2][4][4];
#pragma unroll
  for (int ph = 0; ph < 2; ++ph)
#pragma unroll
    for (int i = 0; i < 4; ++i)
#pragma unroll
      for (int s = 0; s < 4; ++s)
        breg[ph][i][s] = *(const bf16x8*)(Wl + (size_t)(s * 1024 + j0 + r16) * KCAT +
                                          ph * 1024 + (i * 8 + w) * 32 + 8 * g);

  // ---- pointwise-role constants (register-resident) ----
  const int pr = tid >> 4, pjj = tid & 15, phj = j0 + pjj;
  const int prt = pr >> 4, preg = pr & 3;
  const int planec = ((pr & 15) >> 2) * 16 + pjj;
  const float bl0 = bias[l * G4 + phj];
  const float bl1 = bias[l * G4 + 1024 + phj];
  const float bl2 = bias[l * G4 + 2048 + phj];
  const float bl3 = bias[l * G4 + 3072 + phj];
  const float wicv = wic[l * HID + phj];
  const float wfcv = wfc[l * HID + phj];
  const float wocv = woc[l * HID + phj];
  float creg = c0[(size_t)l * NBATCH * HID + (size_t)pr * HID + phj];

#pragma unroll 1
  for (int sl = 0; sl < TT + 3; ++sl) {
    const int t = sl - l;
    if (t >= 0 && t < TT) {
      f32x4 acc[2][4];
#pragma unroll
      for (int a = 0; a < 2; ++a)
#pragma unroll
        for (int b = 0; b < 4; ++b) acc[a][b] = (f32x4){0.f, 0.f, 0.f, 0.f};

      // phase 0: input half
      {
        const uint16_t* s0 = (l == 0)
                                 ? xbf + (size_t)t * (NBATCH * HID)
                                 : ring + ((size_t)(l - 1) * 2 + (t & 1)) * (NBATCH * HID);
#pragma unroll
        for (int i = 0; i < 4; ++i) {
          const int k0 = (i * 8 + w) * 32;
          bf16x8 a0 = *(const bf16x8*)(s0 + r16 * HID + k0 + 8 * g);
          bf16x8 a1 = *(const bf16x8*)(s0 + (r16 + 16) * HID + k0 + 8 * g);
#pragma unroll
          for (int s = 0; s < 4; ++s) {
            acc[0][s] = mfma16x16(a0, breg[0][i][s], acc[0][s]);
            acc[1][s] = mfma16x16(a1, breg[0][i][s], acc[1][s]);
          }
        }
      }
      // phase 1: own m_{t-1}
      if (t > 0) {
        const uint16_t* s1 = (l < 3)
                                 ? ring + ((size_t)l * 2 + ((t - 1) & 1)) * (NBATCH * HID)
                                 : m3 + (size_t)(t - 1) * (NBATCH * HID);
#pragma unroll
        for (int i = 0; i < 4; ++i) {
          const int k0 = (i * 8 + w) * 32;
          bf16x8 a0 = *(const bf16x8*)(s1 + r16 * HID + k0 + 8 * g);
          bf16x8 a1 = *(const bf16x8*)(s1 + (r16 + 16) * HID + k0 + 8 * g);
#pragma unroll
          for (int s = 0; s < 4; ++s) {
            acc[0][s] = mfma16x16(a0, breg[1][i][s], acc[0][s]);
            acc[1][s] = mfma16x16(a1, breg[1][i][s], acc[1][s]);
          }
        }
      }

      // cross-wave reduce
#pragma unroll
      for (int rt = 0; rt < 2; ++rt)
#pragma unroll
        for (int s = 0; s < 4; ++s)
          *(f32x4*)(red + (size_t)((w * 8 + rt * 4 + s) * 64 + lane) * 4) = acc[rt][s];
      __syncthreads();

      float gate[4];
#pragma unroll
      for (int s = 0; s < 4; ++s) {
        float v = 0.f;
#pragma unroll
        for (int w2 = 0; w2 < 8; ++w2)
          v += red[(size_t)((w2 * 8 + prt * 4 + s) * 64 + planec) * 4 + preg];
        gate[s] = v;
      }
      float ai = gate[0] + bl0, af = gate[1] + bl1, ag = gate[2] + bl2, ao = gate[3] + bl3;
      if (t == 0) {
        const float* r0l = r0 + ((size_t)l * NBATCH + pr) * G4;
        ai += r0l[phj];
        af += r0l[1024 + phj];
        ag += r0l[2048 + phj];
        ao += r0l[3072 + phj];
      }
      float iv = sigm(ai + creg * wicv);
      float fv = sigm(af + creg * wfcv);
      float gv = tanh_(ag);
      float nc = fv * creg + iv * gv;
      float ov = sigm(ao + nc * wocv);
      float mv = ov * tanh_(nc);
      creg = nc;
      uint16_t* mout =
          ((l < 3) ? ring + ((size_t)l * 2 + (t & 1)) * (NBATCH * HID)
                   : m3 + (size_t)t * (NBATCH * HID)) +
          (size_t)pr * HID;
      mout[phj] = f2bf(mv);
    }
    grid_barrier(sync);
  }

  // final cell state -> output
  cs[(size_t)l * NBATCH * HID + (size_t)pr * HID + phj] = creg;
}

// ---------------- host ----------------
extern "C" void kernel_launch(void* const* d_in, const int* in_sizes, int n_in, void* d_out,
                              int out_size, void* d_ws, size_t ws_size, hipStream_t stream) {
  (void)in_sizes; (void)n_in; (void)out_size; (void)ws_size;
  const float* x = (const float*)d_in[0];
  const float* h0 = (const float*)d_in[1];
  const float* c0 = (const float*)d_in[2];
  const float* wih = (const float*)d_in[3];
  const float* whh = (const float*)d_in[4];
  const float* bih = (const float*)d_in[5];
  const float* bhh = (const float*)d_in[6];
  const float* wic = (const float*)d_in[7];
  const float* wfc = (const float*)d_in[8];
  const float* woc = (const float*)d_in[9];
  const float* whm = (const float*)d_in[10];

  float* ys = (float*)d_out;
  float* hs = ys + (size_t)TT * NBATCH * HID;
  float* cs = hs + (size_t)4 * NBATCH * HID;

  uint8_t* ws = (uint8_t*)d_ws;
  uint16_t* Wcat = (uint16_t*)(ws);
  uint16_t* m3 = (uint16_t*)(ws + 67108864ull);
  uint16_t* wihT = m3;  // alias (precompute only)
  uint16_t* xbf = (uint16_t*)(ws + 100663296ull);
  uint16_t* whhT = xbf;  // alias (precompute only)
  uint16_t* whm_bf = (uint16_t*)(ws + 134217728ull);
  uint16_t* whmT = (uint16_t*)(ws + 142606336ull);
  uint16_t* ring = (uint16_t*)(ws + 150994944ull);
  float* r0 = (float*)(ws + 151388160ull);
  float* bias = (float*)(ws + 153485312ull);
  uint32_t* sync = (uint32_t*)(ws + 153550848ull);

  hipMemsetAsync(sync, 0, 1024, stream);
  add_bias<<<64, 256, 0, stream>>>(bih, bhh, bias, 4 * G4);
  cast_bf16<<<2048, 256, 0, stream>>>(whm, whm_bf, 524288);
  for (int l = 0; l < 4; ++l)
    transpose_cast<<<dim3(16, 16), 256, 0, stream>>>(whm + (size_t)l * 1048576, 1024,
                                                     whmT + (size_t)l * 1048576, 1024);
  transpose_cast<<<dim3(16, 64), 256, 0, stream>>>(wih, G4, Wcat, KCAT);
  for (int l = 1; l < 4; ++l)
    transpose_cast<<<dim3(16, 64), 256, 0, stream>>>(wih + (size_t)l * 4194304, G4,
                                                     wihT + (size_t)(l - 1) * 4194304, 1024);
  for (int l = 0; l < 4; ++l)
    transpose_cast<<<dim3(16, 64), 256, 0, stream>>>(whh + (size_t)l * 4194304, G4,
                                                     whhT + (size_t)l * 4194304, 1024);
  for (int l = 1; l < 4; ++l)
    gemm_tn<true><<<dim3(32, 8), 256, 0, stream>>>(
        wihT + (size_t)(l - 1) * 4194304, 1024, 4096, whm_bf + (size_t)(l - 1) * 1048576, 1024,
        Wcat + (size_t)l * 8388608, KCAT, 1024);
  for (int l = 0; l < 4; ++l)
    gemm_tn<true><<<dim3(32, 8), 256, 0, stream>>>(
        whhT + (size_t)l * 4194304, 1024, 4096, whm_bf + (size_t)l * 1048576, 1024,
        Wcat + (size_t)l * 8388608 + 1024, KCAT, 1024);
  for (int l = 0; l < 4; ++l)
    gemm32_f32<<<64, 256, 0, stream>>>(h0 + (size_t)l * 32768, 1024,
                                       whh + (size_t)l * 4194304, G4, r0 + (size_t)l * 131072,
                                       G4, 1024);
  cast_bf16<<<8192, 256, 0, stream>>>(x, xbf, 2097152);

  // the whole recurrence in one cooperative persistent kernel
  {
    const uint16_t* a0 = xbf;
    const float* a1 = wic;
    const float* a2 = wfc;
    const float* a3 = woc;
    const float* a4 = r0;
    const float* a5 = bias;
    const float* a6 = c0;
    float* a7 = cs;
    const uint16_t* a8 = Wcat;
    uint16_t* a9 = ring;
    uint16_t* a10 = m3;
    uint32_t* a11 = sync;
    void* args[] = {&a0, &a1, &a2, &a3, &a4, &a5, &a6, &a7, &a8, &a9, &a10, &a11};
    hipLaunchCooperativeKernel((const void*)lstm_persist, dim3(256), dim3(512), args, 0,
                               stream);
  }

  // ys = M3 @ whm3
  gemm_tn<false><<<dim3(128, 8), 256, 0, stream>>>(m3, 1024, 16384,
                                                   whmT + (size_t)3 * 1048576, 1024, ys, 1024,
                                                   1024);
  // hT^l = m_last^l @ whm^l
  for (int l = 0; l < 4; ++l) {
    const uint16_t* mlast = (l < 3) ? ring + ((size_t)l * 2 + 1) * (NBATCH * HID)
                                    : m3 + (size_t)(TT - 1) * (NBATCH * HID);
    gemm_tn<false><<<dim3(1, 8), 256, 0, stream>>>(mlast, 1024, 32,
                                                   whmT + (size_t)l * 1048576, 1024,
                                                   hs + (size_t)l * 32768, 1024, 1024);
  }
}